// Round 22
// baseline (1062.639 us; speedup 1.0000x reference)
//
#include <hip/hip_runtime.h>

constexpr int IMG = 1024;
constexpr long long HW = (long long)IMG * IMG;

typedef unsigned short u16;
typedef __attribute__((ext_vector_type(8))) short bf16x8;
typedef __attribute__((ext_vector_type(4))) float f32x4;
typedef __attribute__((ext_vector_type(4))) u16 u16x4;
typedef __attribute__((ext_vector_type(8))) u16 u16x8;

__device__ __forceinline__ int reflect_idx(int i, int n) {
    if (i < 0) i = -i;
    if (i >= n) i = 2 * n - 2 - i;
    return i;
}
__device__ __forceinline__ int iclamp(int v, int lo, int hi) {
    return v < lo ? lo : (v > hi ? hi : v);
}
__device__ __forceinline__ u16 f2bf(float f) {
    unsigned u = __builtin_bit_cast(unsigned, f);
    u += 0x7FFF + ((u >> 16) & 1);
    return (u16)(u >> 16);
}
__device__ __forceinline__ float bf2f(u16 v) {
    unsigned u = ((unsigned)v) << 16;
    return __builtin_bit_cast(float, u);
}

// ---------------- merged weight prepack (one launch) ----------------
__global__ void prep_all(
    const float* __restrict__ w1, const float* __restrict__ w2,
    const float* __restrict__ w3, const float* __restrict__ w4,
    u16* __restrict__ w1p, u16* __restrict__ w2p,
    u16* __restrict__ w3p, u16* __restrict__ w4p)
{
    int i = blockIdx.x * 256 + threadIdx.x;
    if (i < 25088) {                               // w1p [tap49][co16][ci32]
        int tap = i / (16 * 32), rem = i % (16 * 32), co = rem / 32, ci = rem % 32;
        w1p[i] = (ci < 20) ? f2bf(w1[(co * 20 + ci) * 49 + tap]) : (u16)0;
        return;
    }
    i -= 25088;
    if (i < 13312) {                               // w2p [pair13][co32][k32]
        int p = i / (32 * 32), rem = i % (32 * 32), co = rem / 32, k = rem % 32;
        int tap = 2 * p + (k >> 4), ci = k & 15;
        w2p[i] = (tap < 25) ? f2bf(w2[(co * 16 + ci) * 25 + tap]) : (u16)0;
        return;
    }
    i -= 13312;
    if (i < 51200) {                               // w3p [tap25][co64][ci32]
        int tap = i / (64 * 32), rem = i % (64 * 32), co = rem / 32, ci = rem % 32;
        w3p[i] = f2bf(w3[(co * 32 + ci) * 25 + tap]);
        return;
    }
    i -= 51200;
    if (i < 51200) {                               // w4p [tap25][co32pad][ci64]
        int tap = i / (32 * 64), rem = i % (32 * 64), co = rem / 64, ci = rem % 64;
        w4p[i] = (co < 24) ? f2bf(w4[(co * 64 + ci) * 25 + tap]) : (u16)0;
    }
}

// ---------------- conv1 MFMA: 20(pad32)->16, 7x7, planar fp32 in, CL bf16 out
__global__ __launch_bounds__(256) void conv1_mfma(
    const float* __restrict__ x, const u16* __restrict__ w1p,
    const float* __restrict__ b1, u16* __restrict__ h1, long long h1s,
    int out_base, int out_rows)
{
    constexpr int TS = 22, PAD = 3, UNITS = 4;
    __shared__ u16 tile[TS * TS * 32];           // 31 KB

    const int tid = threadIdx.x;
    const int gx0 = blockIdx.x * 16;
    const int gy0 = out_base + blockIdx.y * 16;
    x  += (long long)blockIdx.z * 20 * HW;
    h1 += (long long)blockIdx.z * h1s;

    for (int u = tid; u < TS * TS * UNITS; u += 256) {
        int pu = u >> 2, q = u & 3;
        int ty = pu / TS, tx = pu - ty * TS;
        int gy = reflect_idx(gy0 + ty - PAD, IMG);
        int gx = reflect_idx(gx0 + tx - PAD, IMG);
        long long off = (long long)gy * IMG + gx;
        bf16x8 v;
        #pragma unroll
        for (int j = 0; j < 8; ++j) {
            int cc = q * 8 + j;
            float f = (cc < 20) ? x[(long long)cc * HW + off] : 0.f;
            v[j] = (short)f2bf(f);
        }
        *(bf16x8*)&tile[(pu * UNITS + (q ^ (tx & 3))) * 8] = v;
    }
    __syncthreads();

    const int lane = tid & 63, wv = tid >> 6;
    const int l15 = lane & 15, g = lane >> 4;

    f32x4 acc[4];
    #pragma unroll
    for (int y = 0; y < 4; ++y) acc[y] = (f32x4){0.f, 0.f, 0.f, 0.f};

    const u16* wp = w1p;
    for (int dx = 0; dx < 7; ++dx) {
        asm volatile("" : "+s"(wp));             // re-opaque per dx: no cross-dx hoist
        bf16x8 af[7];
        #pragma unroll
        for (int dy = 0; dy < 7; ++dy)
            af[dy] = *(const bf16x8*)&wp[((dy * 7 + dx) * 16 + l15) * 32 + g * 8];
        bf16x8 bfr[10];
        const int tx = l15 + dx;
        #pragma unroll
        for (int r = 0; r < 10; ++r)
            bfr[r] = *(const bf16x8*)&tile[(((wv * 4 + r) * TS + tx) * UNITS + (g ^ (tx & 3))) * 8];
        #pragma unroll
        for (int yy = 0; yy < 4; ++yy)
            #pragma unroll
            for (int dy = 0; dy < 7; ++dy)
                acc[yy] = __builtin_amdgcn_mfma_f32_16x16x32_bf16(af[dy], bfr[yy + dy], acc[yy], 0, 0, 0);
    }

    const int out_hi = out_base + out_rows;
    float bia[4];
    #pragma unroll
    for (int r = 0; r < 4; ++r) bia[r] = b1[4 * g + r];
    #pragma unroll
    for (int yy = 0; yy < 4; ++yy) {
        int gy = gy0 + wv * 4 + yy;
        if (gy >= out_hi) continue;
        u16x4 pk;
        #pragma unroll
        for (int r = 0; r < 4; ++r)
            pk[r] = f2bf(fmaxf(acc[yy][r] + bia[r], 0.f));
        *(u16x4*)&h1[((long long)(gy - out_base) * IMG + gx0 + l15) * 16 + 4 * g] = pk;
    }
}

// ---------------- conv2 MFMA: 16->32, 5x5, K=2taps*16ci, CL bf16 ----------
__global__ __launch_bounds__(256) void conv2_mfma(
    const u16* __restrict__ h1, const u16* __restrict__ w2p,
    const float* __restrict__ b2, u16* __restrict__ h2,
    long long h1s, long long h2s,
    int in_base, int in_rows, int out_base, int out_rows)
{
    constexpr int TS = 20, PAD = 2, UNITS = 2;
    __shared__ u16 tile[TS * TS * 16];           // 12.8 KB

    const int tid = threadIdx.x;
    const int gx0 = blockIdx.x * 16;
    const int gy0 = out_base + blockIdx.y * 16;
    h1 += (long long)blockIdx.z * h1s;
    h2 += (long long)blockIdx.z * h2s;

    for (int u = tid; u < TS * TS * UNITS; u += 256) {
        int pu = u >> 1, q = u & 1;
        int ty = pu / TS, tx = pu - ty * TS;
        int gy = reflect_idx(gy0 + ty - PAD, IMG) - in_base;
        gy = iclamp(gy, 0, in_rows - 1);
        int gx = reflect_idx(gx0 + tx - PAD, IMG);
        bf16x8 v = *(const bf16x8*)&h1[((long long)gy * IMG + gx) * 16 + q * 8];
        *(bf16x8*)&tile[(pu * UNITS + (q ^ (tx & 1))) * 8] = v;
    }
    __syncthreads();

    const int lane = tid & 63, wv = tid >> 6;
    const int l15 = lane & 15, g = lane >> 4;

    f32x4 acc[4][2];
    #pragma unroll
    for (int y = 0; y < 4; ++y) {
        acc[y][0] = (f32x4){0.f, 0.f, 0.f, 0.f};
        acc[y][1] = (f32x4){0.f, 0.f, 0.f, 0.f};
    }

    for (int p = 0; p < 13; ++p) {
        int tap = 2 * p + (g >> 1);
        int tb = tap > 24 ? 24 : tap;            // pad tap: A is zero, B content irrelevant
        int dy = tb / 5, dx = tb - dy * 5;
        bf16x8 af0 = *(const bf16x8*)&w2p[(p * 32 + l15) * 32 + g * 8];
        bf16x8 af1 = *(const bf16x8*)&w2p[(p * 32 + 16 + l15) * 32 + g * 8];
        const int tx = l15 + dx;
        #pragma unroll
        for (int yy = 0; yy < 4; ++yy) {
            int ty = wv * 4 + yy + dy;
            bf16x8 bf = *(const bf16x8*)&tile[((ty * TS + tx) * UNITS + ((g & 1) ^ (tx & 1))) * 8];
            acc[yy][0] = __builtin_amdgcn_mfma_f32_16x16x32_bf16(af0, bf, acc[yy][0], 0, 0, 0);
            acc[yy][1] = __builtin_amdgcn_mfma_f32_16x16x32_bf16(af1, bf, acc[yy][1], 0, 0, 0);
        }
    }

    const int out_hi = out_base + out_rows;
    #pragma unroll
    for (int yy = 0; yy < 4; ++yy) {
        int gy = gy0 + wv * 4 + yy;
        if (gy >= out_hi) continue;
        long long pb = ((long long)(gy - out_base) * IMG + gx0 + l15) * 32;
        #pragma unroll
        for (int cb = 0; cb < 2; ++cb) {
            int co = cb * 16 + 4 * g;
            u16x4 pk;
            #pragma unroll
            for (int r = 0; r < 4; ++r)
                pk[r] = f2bf(fmaxf(acc[yy][cb][r] + b2[co + r], 0.f));
            *(u16x4*)&h2[pb + co] = pk;
        }
    }
}

// ---------------- conv3 MFMA: 32->64, 5x5, pipelined 4-tile, 32-wide --------
// Tile = 16 rows x 32 cols (staged 20x36, 45KB x2): halo 1.41x, barriers per
// output px halved, 800 MFMAs per stage-drain. Opaque wp per-dy contains the
// tap hoist (acc 128 + bf 64 + af 16 ~= 210 live).
__global__ __launch_bounds__(256) void conv3_mfma(
    const u16* __restrict__ h2, const u16* __restrict__ w3p,
    const float* __restrict__ b3, u16* __restrict__ h3,
    long long h2s, long long h3s,
    int in_base, int in_rows, int out_base, int out_rows)
{
    constexpr int CI = 32, TSY = 20, TSX = 36, PAD = 2, UNITS = 4;
    __shared__ u16 tileA[TSY * TSX * CI];        // 45 KB (even tiles)
    __shared__ u16 tileB[TSY * TSX * CI];        // 45 KB (odd tiles)

    const int tid = threadIdx.x;
    const int gx0 = blockIdx.x * 32;
    const int gy0_0 = out_base + blockIdx.y * 64;
    const int lane = tid & 63, wv = tid >> 6;
    const int l15 = lane & 15, g = lane >> 4;
    const int out_hi = out_base + out_rows;
    h2 += (long long)blockIdx.z * h2s;
    h3 += (long long)blockIdx.z * h3s;

    auto STAGE = [&](u16* tl, int gy0) {
        for (int gidx = wv; gidx < 45; gidx += 4) {   // 45 groups x 64 units = 20*36*4
            int j = (gidx << 6) + lane;
            int pu = j >> 2, qq = j & 3;
            int ty = pu / TSX, tx = pu - ty * TSX;
            int gy = iclamp(reflect_idx(gy0 + ty - PAD, IMG) - in_base, 0, in_rows - 1);
            int gx = reflect_idx(gx0 + tx - PAD, IMG);
            const u16* src = &h2[((long long)gy * IMG + gx) * CI + ((qq ^ (tx & 3)) << 3)];
            __builtin_amdgcn_global_load_lds(
                (const __attribute__((address_space(1))) void*)src,
                (__attribute__((address_space(3))) void*)&tl[(long long)gidx << 9],
                16, 0, 0);
        }
    };

    auto COMPUTE_EPI = [&](const u16* tl, int gy0) {
        f32x4 acc[4][4][2];                       // [row][co_blk][col_half]
        #pragma unroll
        for (int y = 0; y < 4; ++y)
            #pragma unroll
            for (int cb = 0; cb < 4; ++cb) {
                acc[y][cb][0] = (f32x4){0.f, 0.f, 0.f, 0.f};
                acc[y][cb][1] = (f32x4){0.f, 0.f, 0.f, 0.f};
            }

        const u16* wp = w3p;
        for (int dx = 0; dx < 5; ++dx) {
            const int txL = l15 + dx;
            const int txR = txL + 16;             // (txR&3)==(txL&3)
            const int uu = g ^ (txL & 3);
            bf16x8 bfL[8], bfR[8];
            #pragma unroll
            for (int s = 0; s < 8; ++s) {
                bfL[s] = *(const bf16x8*)&tl[(((wv * 4 + s) * TSX + txL) * UNITS + uu) * 8];
                bfR[s] = *(const bf16x8*)&tl[(((wv * 4 + s) * TSX + txR) * UNITS + uu) * 8];
            }
            #pragma unroll
            for (int dy = 0; dy < 5; ++dy) {
                asm volatile("" : "+s"(wp));     // re-opaque per dy: no hoist
                const int tap = dy * 5 + dx;
                bf16x8 af[4];
                #pragma unroll
                for (int cb = 0; cb < 4; ++cb)
                    af[cb] = *(const bf16x8*)&wp[(tap * 64 + cb * 16 + l15) * 32 + g * 8];
                #pragma unroll
                for (int yy = 0; yy < 4; ++yy)
                    #pragma unroll
                    for (int cb = 0; cb < 4; ++cb) {
                        acc[yy][cb][0] = __builtin_amdgcn_mfma_f32_16x16x32_bf16(af[cb], bfL[yy + dy], acc[yy][cb][0], 0, 0, 0);
                        acc[yy][cb][1] = __builtin_amdgcn_mfma_f32_16x16x32_bf16(af[cb], bfR[yy + dy], acc[yy][cb][1], 0, 0, 0);
                    }
            }
        }

        #pragma unroll
        for (int ch = 0; ch < 2; ++ch) {
            const int col = gx0 + ch * 16 + l15;
            #pragma unroll
            for (int yy = 0; yy < 4; ++yy) {
                int gy = gy0 + wv * 4 + yy;
                if (gy >= out_hi) continue;
                long long pb = ((long long)(gy - out_base) * IMG + col) * 64;
                #pragma unroll
                for (int cb = 0; cb < 4; ++cb) {
                    int co = cb * 16 + 4 * g;
                    u16x4 pk;
                    #pragma unroll
                    for (int r = 0; r < 4; ++r)
                        pk[r] = f2bf(fmaxf(acc[yy][cb][ch][r] + b3[co + r], 0.f));
                    *(u16x4*)&h3[pb + co] = pk;
                }
            }
        }
    };

    STAGE(tileA, gy0_0);
    for (int t = 0; t < 4; ++t) {
        const int gy0 = gy0_0 + t * 16;
        if (gy0 >= out_hi) break;                 // block-uniform: safe with barriers
        const u16* cur  = (t & 1) ? tileB : tileA;
        u16*       next = (t & 1) ? tileA : tileB;
        __syncthreads();                          // drain cur's stage; next's readers done
        if (t < 3) STAGE(next, gy0 + 16);
        COMPUTE_EPI(cur, gy0);
    }
}

// ---------------- conv4 MFMA: 64->24(+8 pad), 5x5 + softmax, 32-wide tiles --
__global__ __launch_bounds__(256) void conv4_mfma(
    const u16* __restrict__ h3, const u16* __restrict__ w4p,
    const float* __restrict__ b4, float* __restrict__ out,
    u16* __restrict__ wsoft, long long h3s, long long wss,
    int in_base, int in_rows, int row0, int nrows)
{
    constexpr int CI = 64, TSY = 20, TSX = 36, PAD = 2, UNITS = 4;
    __shared__ u16 tileA[TSY * TSX * 32];        // 45 KB (even steps)
    __shared__ u16 tileB[TSY * TSX * 32];        // 45 KB (odd steps)

    const int tid = threadIdx.x;
    const int gx0 = blockIdx.x * 32;
    const int gy0_0 = row0 + blockIdx.y * 64;
    const int lane = tid & 63, wv = tid >> 6;
    const int l15 = lane & 15, g = lane >> 4;
    h3    += (long long)blockIdx.z * h3s;
    out   += (long long)blockIdx.z * 11 * HW;
    wsoft += (long long)blockIdx.z * wss;

    auto STAGE = [&](u16* tl, int gy0, int half) {
        for (int gidx = wv; gidx < 45; gidx += 4) {   // 45 groups x 64 units = 20*36*4
            int j = (gidx << 6) + lane;
            int pu = j >> 2, qq = j & 3;
            int ty = pu / TSX, tx = pu - ty * TSX;
            int gy = iclamp(reflect_idx(gy0 + ty - PAD, IMG) - in_base, 0, in_rows - 1);
            int gx = reflect_idx(gx0 + tx - PAD, IMG);
            const u16* src = &h3[((long long)gy * IMG + gx) * CI + half * 32 + ((qq ^ (tx & 3)) << 3)];
            __builtin_amdgcn_global_load_lds(
                (const __attribute__((address_space(1))) void*)src,
                (__attribute__((address_space(3))) void*)&tl[(long long)gidx << 9],
                16, 0, 0);
        }
    };

    auto COMPUTE = [&](const u16* tl, int half, f32x4 (&acc)[4][2][2]) {
        for (int dx = 0; dx < 5; ++dx) {
            const int txL = l15 + dx;             // left col-half
            const int txR = txL + 16;             // right col-half ((txR&3)==(txL&3))
            const int uu = g ^ (txL & 3);
            bf16x8 bfL[8], bfR[8];
            #pragma unroll
            for (int s = 0; s < 8; ++s) {
                bfL[s] = *(const bf16x8*)&tl[(((wv * 4 + s) * TSX + txL) * UNITS + uu) * 8];
                bfR[s] = *(const bf16x8*)&tl[(((wv * 4 + s) * TSX + txR) * UNITS + uu) * 8];
            }
            #pragma unroll
            for (int dy = 0; dy < 5; ++dy) {
                const int tap = dy * 5 + dx;
                bf16x8 af0 = *(const bf16x8*)&w4p[(tap * 32 + l15) * 64 + half * 32 + g * 8];
                bf16x8 af1 = *(const bf16x8*)&w4p[(tap * 32 + 16 + l15) * 64 + half * 32 + g * 8];
                #pragma unroll
                for (int yy = 0; yy < 4; ++yy) {
                    acc[yy][0][0] = __builtin_amdgcn_mfma_f32_16x16x32_bf16(af0, bfL[yy + dy], acc[yy][0][0], 0, 0, 0);
                    acc[yy][1][0] = __builtin_amdgcn_mfma_f32_16x16x32_bf16(af1, bfL[yy + dy], acc[yy][1][0], 0, 0, 0);
                    acc[yy][0][1] = __builtin_amdgcn_mfma_f32_16x16x32_bf16(af0, bfR[yy + dy], acc[yy][0][1], 0, 0, 0);
                    acc[yy][1][1] = __builtin_amdgcn_mfma_f32_16x16x32_bf16(af1, bfR[yy + dy], acc[yy][1][1], 0, 0, 0);
                }
            }
        }
    };

    float bia0[4], bia1[4];
    #pragma unroll
    for (int r = 0; r < 4; ++r) {
        bia0[r] = b4[4 * g + r];
        int c1 = 16 + 4 * g + r;
        bia1[r] = (c1 < 24) ? b4[c1] : 0.f;
    }

    STAGE(tileA, gy0_0, 0);
    for (int t = 0; t < 4; ++t) {
        const int gy0 = gy0_0 + t * 16;
        f32x4 acc[4][2][2];                       // [row][co_blk][col_half]
        #pragma unroll
        for (int y = 0; y < 4; ++y)
            #pragma unroll
            for (int cb = 0; cb < 2; ++cb) {
                acc[y][cb][0] = (f32x4){0.f, 0.f, 0.f, 0.f};
                acc[y][cb][1] = (f32x4){0.f, 0.f, 0.f, 0.f};
            }

        __syncthreads();                          // drain A(half0); B readers done
        STAGE(tileB, gy0, 1);
        COMPUTE(tileA, 0, acc);
        __syncthreads();                          // drain B(half1); A readers done
        if (t < 3) STAGE(tileA, gy0 + 16, 0);
        COMPUTE(tileB, 1, acc);

        // epilogue per column-half: bias + hidden + softmax + bf16 wsoft store
        #pragma unroll
        for (int ch = 0; ch < 2; ++ch) {
            const int col = gx0 + ch * 16 + l15;
            #pragma unroll
            for (int yy = 0; yy < 4; ++yy) {
                int gy = gy0 + wv * 4 + yy;
                long long pg = (long long)gy * IMG + col;
                float v0[4], v1[4];
                #pragma unroll
                for (int r = 0; r < 4; ++r) {
                    v0[r] = acc[yy][0][ch][r] + bia0[r];
                    v1[r] = acc[yy][1][ch][r] + bia1[r];
                }
                if (g < 2) {
                    #pragma unroll
                    for (int r = 0; r < 4; ++r)
                        out[(long long)(3 + 4 * g + r) * HW + pg] = v0[r];
                }
                float s[4];
                int kbase;
                if (g < 2) {
                    kbase = 8 + 4 * g;
                    #pragma unroll
                    for (int r = 0; r < 4; ++r) s[r] = v1[r] * 0.2f;
                } else {
                    kbase = 4 * (g - 2);
                    #pragma unroll
                    for (int r = 0; r < 4; ++r) s[r] = v0[r] * 0.2f;
                }
                float m = fmaxf(fmaxf(s[0], s[1]), fmaxf(s[2], s[3]));
                m = fmaxf(m, __shfl_xor(m, 16));
                m = fmaxf(m, __shfl_xor(m, 32));
                float e[4], loc = 0.f;
                #pragma unroll
                for (int r = 0; r < 4; ++r) { e[r] = __expf(s[r] - m); loc += e[r]; }
                loc += __shfl_xor(loc, 16);
                loc += __shfl_xor(loc, 32);
                float inv = 1.f / loc;
                long long pl = (long long)(gy - row0) * IMG + col;
                u16x4 pk;
                #pragma unroll
                for (int r = 0; r < 4; ++r) pk[r] = f2bf(e[r] * inv);
                *(u16x4*)&wsoft[pl * 16 + kbase] = pk;
            }
        }
    }
}

// ---------------- filter v3: bf16 channel-last wsoft, 4 px/thread ----------
__global__ __launch_bounds__(256) void apply_filter(
    const float* __restrict__ x, const float* __restrict__ dwk,
    const u16* __restrict__ wsoft, float* __restrict__ out,
    long long wss, int row0, int nrows)
{
    constexpr int PAD = 4, TSF = 40;             // 32+8
    __shared__ float ctile[3][TSF * TSF];        // 19.2 KB

    const int tid = threadIdx.x;
    const int tx = tid & 7, ty = tid >> 3;
    const int bx = blockIdx.x * 32;
    const int gy0 = row0 + blockIdx.y * 32;
    x     += (long long)blockIdx.z * 20 * HW;
    out   += (long long)blockIdx.z * 11 * HW;
    wsoft += (long long)blockIdx.z * wss;

    for (int c = 0; c < 3; ++c)
        for (int idx = tid; idx < TSF * TSF; idx += 256) {
            int ly = idx / TSF, lx = idx - ly * TSF;
            int gy = gy0 + ly - PAD, gx = bx + lx - PAD;
            float v = 0.f;
            if (gy >= 0 && gy < IMG && gx >= 0 && gx < IMG)
                v = x[(long long)c * HW + (long long)gy * IMG + gx];
            ctile[c][idx] = v;
        }
    __syncthreads();

    const int gy = gy0 + ty;
    const int xq = bx + tx * 4;

    float wreg[16][4];
    #pragma unroll
    for (int p = 0; p < 4; ++p) {
        long long pb = ((long long)(gy - row0) * IMG + xq + p) * 16;
        u16x8 lo = *(const u16x8*)&wsoft[pb];
        u16x8 hi = *(const u16x8*)&wsoft[pb + 8];
        #pragma unroll
        for (int k = 0; k < 8; ++k) {
            wreg[k][p]     = bf2f(lo[k]);
            wreg[8 + k][p] = bf2f(hi[k]);
        }
    }

    float f[3][4];
    #pragma unroll
    for (int c = 0; c < 3; ++c)
        #pragma unroll
        for (int p = 0; p < 4; ++p) f[c][p] = 0.f;

    for (int dy = 0; dy < 9; ++dy) {
        float c9[9][4];
        #pragma unroll
        for (int dxx = 0; dxx < 9; ++dxx)
            #pragma unroll
            for (int p = 0; p < 4; ++p) c9[dxx][p] = 0.f;
        #pragma unroll
        for (int k = 0; k < 16; ++k) {
            #pragma unroll
            for (int dxx = 0; dxx < 9; ++dxx) {
                float s = dwk[k * 81 + dy * 9 + dxx];   // wave-uniform -> s_load
                #pragma unroll
                for (int p = 0; p < 4; ++p) c9[dxx][p] += s * wreg[k][p];
            }
        }
        #pragma unroll
        for (int c = 0; c < 3; ++c) {
            const float* crow = &ctile[c][(ty + dy) * TSF + tx * 4];
            f32x4 q0 = *(const f32x4*)crow;
            f32x4 q1 = *(const f32x4*)(crow + 4);
            f32x4 q2 = *(const f32x4*)(crow + 8);
            float win[12];
            #pragma unroll
            for (int j = 0; j < 4; ++j) { win[j] = q0[j]; win[4 + j] = q1[j]; win[8 + j] = q2[j]; }
            #pragma unroll
            for (int dxx = 0; dxx < 9; ++dxx)
                #pragma unroll
                for (int p = 0; p < 4; ++p)
                    f[c][p] += c9[dxx][p] * win[dxx + p];
        }
    }

    #pragma unroll
    for (int c = 0; c < 3; ++c) {
        f32x4 o = { f[c][0], f[c][1], f[c][2], f[c][3] };
        *(f32x4*)&out[(long long)c * HW + (long long)gy * IMG + xq] = o;
    }
}

static inline int hmax(int a, int b) { return a > b ? a : b; }
static inline int hmin(int a, int b) { return a < b ? a : b; }

extern "C" void kernel_launch(void* const* d_in, const int* in_sizes, int n_in,
                              void* d_out, int out_size, void* d_ws, size_t ws_size,
                              hipStream_t stream) {
    const float* x   = (const float*)d_in[0];
    const float* w1  = (const float*)d_in[1];
    const float* b1  = (const float*)d_in[2];
    const float* w2  = (const float*)d_in[3];
    const float* b2  = (const float*)d_in[4];
    const float* w3  = (const float*)d_in[5];
    const float* b3  = (const float*)d_in[6];
    const float* w4  = (const float*)d_in[7];
    const float* b4  = (const float*)d_in[8];
    const float* dwk = (const float*)d_in[9];
    float* out = (float*)d_out;

    // Both batches resident: footprint is 2x per-batch buffers + weights.
    // R must be a multiple of 64 for the 4-tile pipelined conv3/conv4.
    int R = 64;
    const int cand[5] = {1024, 512, 256, 128, 64};
    for (int i = 0; i < 5; ++i) {
        long long r = cand[i];
        size_t per_batch = 32768ULL * (r + 12) + 65536ULL * (r + 8)
                         + 131072ULL * (r + 4) + 32768ULL * r;
        size_t need = 2 * per_batch + 400000ULL;
        if (need <= ws_size) { R = cand[i]; break; }
    }

    const long long h1s = (long long)(R + 12) * IMG * 16;
    const long long h2s = (long long)(R + 8) * IMG * 32;
    const long long h3s = (long long)(R + 4) * IMG * 64;
    const long long wss = (long long)R * IMG * 16;

    u16* h1    = (u16*)d_ws;                      // 2 x h1s
    u16* h2    = h1 + 2 * h1s;                    // 2 x h2s
    u16* h3    = h2 + 2 * h2s;                    // 2 x h3s
    u16* wsoft = h3 + 2 * h3s;                    // 2 x wss (bf16 CL [px][16])
    u16* w1p   = wsoft + 2 * wss;
    u16* w2p   = w1p + 49 * 16 * 32;
    u16* w3p   = w2p + 13 * 32 * 32;
    u16* w4p   = w3p + 25 * 64 * 32;

    dim3 blk(256);
    prep_all<<<dim3(550), blk, 0, stream>>>(w1, w2, w3, w4, w1p, w2p, w3p, w4p);

    const int nstripes = IMG / R;
    for (int s = 0; s < nstripes; ++s) {
        const int r0 = s * R;
        const int h1_lo = hmax(0, r0 - 6), h1_hi = hmin(IMG, r0 + R + 6), h1_r = h1_hi - h1_lo;
        const int h2_lo = hmax(0, r0 - 4), h2_hi = hmin(IMG, r0 + R + 4), h2_r = h2_hi - h2_lo;
        const int h3_lo = hmax(0, r0 - 2), h3_hi = hmin(IMG, r0 + R + 2), h3_r = h3_hi - h3_lo;

        conv1_mfma<<<dim3(64, (h1_r + 15) / 16, 2), blk, 0, stream>>>(
            x, w1p, b1, h1, h1s, h1_lo, h1_r);
        conv2_mfma<<<dim3(64, (h2_r + 15) / 16, 2), blk, 0, stream>>>(
            h1, w2p, b2, h2, h1s, h2s, h1_lo, h1_r, h2_lo, h2_r);
        conv3_mfma<<<dim3(32, (h3_r + 63) / 64, 2), blk, 0, stream>>>(
            h2, w3p, b3, h3, h2s, h3s, h2_lo, h2_r, h3_lo, h3_r);
        conv4_mfma<<<dim3(32, R / 64, 2), blk, 0, stream>>>(
            h3, w4p, b4, out, wsoft, h3s, wss, h3_lo, h3_r, r0, R);
        apply_filter<<<dim3(32, R / 32, 2), blk, 0, stream>>>(
            x, dwk, wsoft, out, wss, r0, R);
    }
}

// Round 23
// 1023.808 us; speedup vs baseline: 1.0379x; 1.0379x over previous
//
#include <hip/hip_runtime.h>

constexpr int IMG = 1024;
constexpr long long HW = (long long)IMG * IMG;

typedef unsigned short u16;
typedef __attribute__((ext_vector_type(8))) short bf16x8;
typedef __attribute__((ext_vector_type(4))) float f32x4;
typedef __attribute__((ext_vector_type(4))) u16 u16x4;
typedef __attribute__((ext_vector_type(8))) u16 u16x8;

__device__ __forceinline__ int reflect_idx(int i, int n) {
    if (i < 0) i = -i;
    if (i >= n) i = 2 * n - 2 - i;
    return i;
}
__device__ __forceinline__ int iclamp(int v, int lo, int hi) {
    return v < lo ? lo : (v > hi ? hi : v);
}
__device__ __forceinline__ u16 f2bf(float f) {
    unsigned u = __builtin_bit_cast(unsigned, f);
    u += 0x7FFF + ((u >> 16) & 1);
    return (u16)(u >> 16);
}
__device__ __forceinline__ float bf2f(u16 v) {
    unsigned u = ((unsigned)v) << 16;
    return __builtin_bit_cast(float, u);
}

// ---------------- merged weight prepack (one launch) ----------------
__global__ void prep_all(
    const float* __restrict__ w1, const float* __restrict__ w2,
    const float* __restrict__ w3, const float* __restrict__ w4,
    u16* __restrict__ w1p, u16* __restrict__ w2p,
    u16* __restrict__ w3p, u16* __restrict__ w4p)
{
    int i = blockIdx.x * 256 + threadIdx.x;
    if (i < 25088) {                               // w1p [tap49][co16][ci32]
        int tap = i / (16 * 32), rem = i % (16 * 32), co = rem / 32, ci = rem % 32;
        w1p[i] = (ci < 20) ? f2bf(w1[(co * 20 + ci) * 49 + tap]) : (u16)0;
        return;
    }
    i -= 25088;
    if (i < 13312) {                               // w2p [pair13][co32][k32]
        int p = i / (32 * 32), rem = i % (32 * 32), co = rem / 32, k = rem % 32;
        int tap = 2 * p + (k >> 4), ci = k & 15;
        w2p[i] = (tap < 25) ? f2bf(w2[(co * 16 + ci) * 25 + tap]) : (u16)0;
        return;
    }
    i -= 13312;
    if (i < 51200) {                               // w3p [tap25][co64][ci32]
        int tap = i / (64 * 32), rem = i % (64 * 32), co = rem / 32, ci = rem % 32;
        w3p[i] = f2bf(w3[(co * 32 + ci) * 25 + tap]);
        return;
    }
    i -= 51200;
    if (i < 51200) {                               // w4p [tap25][co32pad][ci64]
        int tap = i / (32 * 64), rem = i % (32 * 64), co = rem / 64, ci = rem % 64;
        w4p[i] = (co < 24) ? f2bf(w4[(co * 64 + ci) * 25 + tap]) : (u16)0;
    }
}

// ---------------- conv1 MFMA: 20(pad32)->16, 7x7, planar fp32 in, CL bf16 out
__global__ __launch_bounds__(256) void conv1_mfma(
    const float* __restrict__ x, const u16* __restrict__ w1p,
    const float* __restrict__ b1, u16* __restrict__ h1, long long h1s,
    int out_base, int out_rows)
{
    constexpr int TS = 22, PAD = 3, UNITS = 4;
    __shared__ u16 tile[TS * TS * 32];           // 31 KB

    const int tid = threadIdx.x;
    const int gx0 = blockIdx.x * 16;
    const int gy0 = out_base + blockIdx.y * 16;
    x  += (long long)blockIdx.z * 20 * HW;
    h1 += (long long)blockIdx.z * h1s;

    for (int u = tid; u < TS * TS * UNITS; u += 256) {
        int pu = u >> 2, q = u & 3;
        int ty = pu / TS, tx = pu - ty * TS;
        int gy = reflect_idx(gy0 + ty - PAD, IMG);
        int gx = reflect_idx(gx0 + tx - PAD, IMG);
        long long off = (long long)gy * IMG + gx;
        bf16x8 v;
        #pragma unroll
        for (int j = 0; j < 8; ++j) {
            int cc = q * 8 + j;
            float f = (cc < 20) ? x[(long long)cc * HW + off] : 0.f;
            v[j] = (short)f2bf(f);
        }
        *(bf16x8*)&tile[(pu * UNITS + (q ^ (tx & 3))) * 8] = v;
    }
    __syncthreads();

    const int lane = tid & 63, wv = tid >> 6;
    const int l15 = lane & 15, g = lane >> 4;

    f32x4 acc[4];
    #pragma unroll
    for (int y = 0; y < 4; ++y) acc[y] = (f32x4){0.f, 0.f, 0.f, 0.f};

    const u16* wp = w1p;
    for (int dx = 0; dx < 7; ++dx) {
        asm volatile("" : "+s"(wp));             // re-opaque per dx: no cross-dx hoist
        bf16x8 af[7];
        #pragma unroll
        for (int dy = 0; dy < 7; ++dy)
            af[dy] = *(const bf16x8*)&wp[((dy * 7 + dx) * 16 + l15) * 32 + g * 8];
        bf16x8 bfr[10];
        const int tx = l15 + dx;
        #pragma unroll
        for (int r = 0; r < 10; ++r)
            bfr[r] = *(const bf16x8*)&tile[(((wv * 4 + r) * TS + tx) * UNITS + (g ^ (tx & 3))) * 8];
        #pragma unroll
        for (int yy = 0; yy < 4; ++yy)
            #pragma unroll
            for (int dy = 0; dy < 7; ++dy)
                acc[yy] = __builtin_amdgcn_mfma_f32_16x16x32_bf16(af[dy], bfr[yy + dy], acc[yy], 0, 0, 0);
    }

    const int out_hi = out_base + out_rows;
    float bia[4];
    #pragma unroll
    for (int r = 0; r < 4; ++r) bia[r] = b1[4 * g + r];
    #pragma unroll
    for (int yy = 0; yy < 4; ++yy) {
        int gy = gy0 + wv * 4 + yy;
        if (gy >= out_hi) continue;
        u16x4 pk;
        #pragma unroll
        for (int r = 0; r < 4; ++r)
            pk[r] = f2bf(fmaxf(acc[yy][r] + bia[r], 0.f));
        *(u16x4*)&h1[((long long)(gy - out_base) * IMG + gx0 + l15) * 16 + 4 * g] = pk;
    }
}

// ---------------- conv2 MFMA: 16->32, 5x5, K=2taps*16ci, CL bf16 ----------
__global__ __launch_bounds__(256) void conv2_mfma(
    const u16* __restrict__ h1, const u16* __restrict__ w2p,
    const float* __restrict__ b2, u16* __restrict__ h2,
    long long h1s, long long h2s,
    int in_base, int in_rows, int out_base, int out_rows)
{
    constexpr int TS = 20, PAD = 2, UNITS = 2;
    __shared__ u16 tile[TS * TS * 16];           // 12.8 KB

    const int tid = threadIdx.x;
    const int gx0 = blockIdx.x * 16;
    const int gy0 = out_base + blockIdx.y * 16;
    h1 += (long long)blockIdx.z * h1s;
    h2 += (long long)blockIdx.z * h2s;

    for (int u = tid; u < TS * TS * UNITS; u += 256) {
        int pu = u >> 1, q = u & 1;
        int ty = pu / TS, tx = pu - ty * TS;
        int gy = reflect_idx(gy0 + ty - PAD, IMG) - in_base;
        gy = iclamp(gy, 0, in_rows - 1);
        int gx = reflect_idx(gx0 + tx - PAD, IMG);
        bf16x8 v = *(const bf16x8*)&h1[((long long)gy * IMG + gx) * 16 + q * 8];
        *(bf16x8*)&tile[(pu * UNITS + (q ^ (tx & 1))) * 8] = v;
    }
    __syncthreads();

    const int lane = tid & 63, wv = tid >> 6;
    const int l15 = lane & 15, g = lane >> 4;

    f32x4 acc[4][2];
    #pragma unroll
    for (int y = 0; y < 4; ++y) {
        acc[y][0] = (f32x4){0.f, 0.f, 0.f, 0.f};
        acc[y][1] = (f32x4){0.f, 0.f, 0.f, 0.f};
    }

    for (int p = 0; p < 13; ++p) {
        int tap = 2 * p + (g >> 1);
        int tb = tap > 24 ? 24 : tap;            // pad tap: A is zero, B content irrelevant
        int dy = tb / 5, dx = tb - dy * 5;
        bf16x8 af0 = *(const bf16x8*)&w2p[(p * 32 + l15) * 32 + g * 8];
        bf16x8 af1 = *(const bf16x8*)&w2p[(p * 32 + 16 + l15) * 32 + g * 8];
        const int tx = l15 + dx;
        #pragma unroll
        for (int yy = 0; yy < 4; ++yy) {
            int ty = wv * 4 + yy + dy;
            bf16x8 bf = *(const bf16x8*)&tile[((ty * TS + tx) * UNITS + ((g & 1) ^ (tx & 1))) * 8];
            acc[yy][0] = __builtin_amdgcn_mfma_f32_16x16x32_bf16(af0, bf, acc[yy][0], 0, 0, 0);
            acc[yy][1] = __builtin_amdgcn_mfma_f32_16x16x32_bf16(af1, bf, acc[yy][1], 0, 0, 0);
        }
    }

    const int out_hi = out_base + out_rows;
    #pragma unroll
    for (int yy = 0; yy < 4; ++yy) {
        int gy = gy0 + wv * 4 + yy;
        if (gy >= out_hi) continue;
        long long pb = ((long long)(gy - out_base) * IMG + gx0 + l15) * 32;
        #pragma unroll
        for (int cb = 0; cb < 2; ++cb) {
            int co = cb * 16 + 4 * g;
            u16x4 pk;
            #pragma unroll
            for (int r = 0; r < 4; ++r)
                pk[r] = f2bf(fmaxf(acc[yy][cb][r] + b2[co + r], 0.f));
            *(u16x4*)&h2[pb + co] = pk;
        }
    }
}

// ---------------- conv3 MFMA: 32->64, 5x5, pipelined 4-tile + opaque wp -----
// 16-wide tiles (R21 optimum; 32-wide regressed: acc 128 + bf 64 blows the
// register slack). Double-buffered DMA pipeline, per-dy opaque weight ptr.
__global__ __launch_bounds__(256) void conv3_mfma(
    const u16* __restrict__ h2, const u16* __restrict__ w3p,
    const float* __restrict__ b3, u16* __restrict__ h3,
    long long h2s, long long h3s,
    int in_base, int in_rows, int out_base, int out_rows)
{
    constexpr int CI = 32, TS = 20, PAD = 2, UNITS = 4;
    __shared__ u16 tileA[TS * TS * CI];          // 25.6 KB (even tiles)
    __shared__ u16 tileB[TS * TS * CI];          // 25.6 KB (odd tiles)

    const int tid = threadIdx.x;
    const int gx0 = blockIdx.x * 16;
    const int gy0_0 = out_base + blockIdx.y * 64;
    const int lane = tid & 63, wv = tid >> 6;
    const int l15 = lane & 15, g = lane >> 4;
    const int out_hi = out_base + out_rows;
    h2 += (long long)blockIdx.z * h2s;
    h3 += (long long)blockIdx.z * h3s;

    auto STAGE = [&](u16* tl, int gy0) {
        for (int gidx = wv; gidx < 25; gidx += 4) {
            int j = (gidx << 6) + lane;
            int pu = j >> 2, qq = j & 3;
            int ty = pu / TS, tx = pu - ty * TS;
            int gy = iclamp(reflect_idx(gy0 + ty - PAD, IMG) - in_base, 0, in_rows - 1);
            int gx = reflect_idx(gx0 + tx - PAD, IMG);
            const u16* src = &h2[((long long)gy * IMG + gx) * CI + ((qq ^ (tx & 3)) << 3)];
            __builtin_amdgcn_global_load_lds(
                (const __attribute__((address_space(1))) void*)src,
                (__attribute__((address_space(3))) void*)&tl[(long long)gidx << 9],
                16, 0, 0);
        }
    };

    auto COMPUTE_EPI = [&](const u16* tl, int gy0) {
        f32x4 acc[4][4];
        #pragma unroll
        for (int y = 0; y < 4; ++y)
            #pragma unroll
            for (int cb = 0; cb < 4; ++cb) acc[y][cb] = (f32x4){0.f, 0.f, 0.f, 0.f};

        const u16* wp = w3p;
        for (int dx = 0; dx < 5; ++dx) {
            const int tx = l15 + dx;
            const int uu = g ^ (tx & 3);
            bf16x8 bfr[8];
            #pragma unroll
            for (int s = 0; s < 8; ++s)
                bfr[s] = *(const bf16x8*)&tl[(((wv * 4 + s) * TS + tx) * UNITS + uu) * 8];
            #pragma unroll
            for (int dy = 0; dy < 5; ++dy) {
                asm volatile("" : "+s"(wp));     // re-opaque per dy: no hoist
                const int tap = dy * 5 + dx;
                bf16x8 af[4];
                #pragma unroll
                for (int cb = 0; cb < 4; ++cb)
                    af[cb] = *(const bf16x8*)&wp[(tap * 64 + cb * 16 + l15) * 32 + g * 8];
                #pragma unroll
                for (int yy = 0; yy < 4; ++yy)
                    #pragma unroll
                    for (int cb = 0; cb < 4; ++cb)
                        acc[yy][cb] = __builtin_amdgcn_mfma_f32_16x16x32_bf16(af[cb], bfr[yy + dy], acc[yy][cb], 0, 0, 0);
            }
        }

        #pragma unroll
        for (int yy = 0; yy < 4; ++yy) {
            int gy = gy0 + wv * 4 + yy;
            if (gy >= out_hi) continue;
            long long pb = ((long long)(gy - out_base) * IMG + gx0 + l15) * 64;
            #pragma unroll
            for (int cb = 0; cb < 4; ++cb) {
                int co = cb * 16 + 4 * g;
                u16x4 pk;
                #pragma unroll
                for (int r = 0; r < 4; ++r)
                    pk[r] = f2bf(fmaxf(acc[yy][cb][r] + b3[co + r], 0.f));
                *(u16x4*)&h3[pb + co] = pk;
            }
        }
    };

    STAGE(tileA, gy0_0);
    for (int t = 0; t < 4; ++t) {
        const int gy0 = gy0_0 + t * 16;
        if (gy0 >= out_hi) break;                 // block-uniform: safe with barriers
        const u16* cur  = (t & 1) ? tileB : tileA;
        u16*       next = (t & 1) ? tileA : tileB;
        __syncthreads();                          // drain cur's stage; next's readers done
        if (t < 3) STAGE(next, gy0 + 16);
        COMPUTE_EPI(cur, gy0);
    }
}

// ---------------- conv4 MFMA: 64->24(+8 pad), 5x5 + softmax, 32-wide tiles --
__global__ __launch_bounds__(256) void conv4_mfma(
    const u16* __restrict__ h3, const u16* __restrict__ w4p,
    const float* __restrict__ b4, float* __restrict__ out,
    u16* __restrict__ wsoft, long long h3s, long long wss,
    int in_base, int in_rows, int row0, int nrows)
{
    constexpr int CI = 64, TSY = 20, TSX = 36, PAD = 2, UNITS = 4;
    __shared__ u16 tileA[TSY * TSX * 32];        // 45 KB (even steps)
    __shared__ u16 tileB[TSY * TSX * 32];        // 45 KB (odd steps)

    const int tid = threadIdx.x;
    const int gx0 = blockIdx.x * 32;
    const int gy0_0 = row0 + blockIdx.y * 64;
    const int lane = tid & 63, wv = tid >> 6;
    const int l15 = lane & 15, g = lane >> 4;
    h3    += (long long)blockIdx.z * h3s;
    out   += (long long)blockIdx.z * 11 * HW;
    wsoft += (long long)blockIdx.z * wss;

    auto STAGE = [&](u16* tl, int gy0, int half) {
        for (int gidx = wv; gidx < 45; gidx += 4) {   // 45 groups x 64 units = 20*36*4
            int j = (gidx << 6) + lane;
            int pu = j >> 2, qq = j & 3;
            int ty = pu / TSX, tx = pu - ty * TSX;
            int gy = iclamp(reflect_idx(gy0 + ty - PAD, IMG) - in_base, 0, in_rows - 1);
            int gx = reflect_idx(gx0 + tx - PAD, IMG);
            const u16* src = &h3[((long long)gy * IMG + gx) * CI + half * 32 + ((qq ^ (tx & 3)) << 3)];
            __builtin_amdgcn_global_load_lds(
                (const __attribute__((address_space(1))) void*)src,
                (__attribute__((address_space(3))) void*)&tl[(long long)gidx << 9],
                16, 0, 0);
        }
    };

    auto COMPUTE = [&](const u16* tl, int half, f32x4 (&acc)[4][2][2]) {
        for (int dx = 0; dx < 5; ++dx) {
            const int txL = l15 + dx;             // left col-half
            const int txR = txL + 16;             // right col-half ((txR&3)==(txL&3))
            const int uu = g ^ (txL & 3);
            bf16x8 bfL[8], bfR[8];
            #pragma unroll
            for (int s = 0; s < 8; ++s) {
                bfL[s] = *(const bf16x8*)&tl[(((wv * 4 + s) * TSX + txL) * UNITS + uu) * 8];
                bfR[s] = *(const bf16x8*)&tl[(((wv * 4 + s) * TSX + txR) * UNITS + uu) * 8];
            }
            #pragma unroll
            for (int dy = 0; dy < 5; ++dy) {
                const int tap = dy * 5 + dx;
                bf16x8 af0 = *(const bf16x8*)&w4p[(tap * 32 + l15) * 64 + half * 32 + g * 8];
                bf16x8 af1 = *(const bf16x8*)&w4p[(tap * 32 + 16 + l15) * 64 + half * 32 + g * 8];
                #pragma unroll
                for (int yy = 0; yy < 4; ++yy) {
                    acc[yy][0][0] = __builtin_amdgcn_mfma_f32_16x16x32_bf16(af0, bfL[yy + dy], acc[yy][0][0], 0, 0, 0);
                    acc[yy][1][0] = __builtin_amdgcn_mfma_f32_16x16x32_bf16(af1, bfL[yy + dy], acc[yy][1][0], 0, 0, 0);
                    acc[yy][0][1] = __builtin_amdgcn_mfma_f32_16x16x32_bf16(af0, bfR[yy + dy], acc[yy][0][1], 0, 0, 0);
                    acc[yy][1][1] = __builtin_amdgcn_mfma_f32_16x16x32_bf16(af1, bfR[yy + dy], acc[yy][1][1], 0, 0, 0);
                }
            }
        }
    };

    float bia0[4], bia1[4];
    #pragma unroll
    for (int r = 0; r < 4; ++r) {
        bia0[r] = b4[4 * g + r];
        int c1 = 16 + 4 * g + r;
        bia1[r] = (c1 < 24) ? b4[c1] : 0.f;
    }

    STAGE(tileA, gy0_0, 0);
    for (int t = 0; t < 4; ++t) {
        const int gy0 = gy0_0 + t * 16;
        f32x4 acc[4][2][2];                       // [row][co_blk][col_half]
        #pragma unroll
        for (int y = 0; y < 4; ++y)
            #pragma unroll
            for (int cb = 0; cb < 2; ++cb) {
                acc[y][cb][0] = (f32x4){0.f, 0.f, 0.f, 0.f};
                acc[y][cb][1] = (f32x4){0.f, 0.f, 0.f, 0.f};
            }

        __syncthreads();                          // drain A(half0); B readers done
        STAGE(tileB, gy0, 1);
        COMPUTE(tileA, 0, acc);
        __syncthreads();                          // drain B(half1); A readers done
        if (t < 3) STAGE(tileA, gy0 + 16, 0);
        COMPUTE(tileB, 1, acc);

        // epilogue per column-half: bias + hidden + softmax + bf16 wsoft store
        #pragma unroll
        for (int ch = 0; ch < 2; ++ch) {
            const int col = gx0 + ch * 16 + l15;
            #pragma unroll
            for (int yy = 0; yy < 4; ++yy) {
                int gy = gy0 + wv * 4 + yy;
                long long pg = (long long)gy * IMG + col;
                float v0[4], v1[4];
                #pragma unroll
                for (int r = 0; r < 4; ++r) {
                    v0[r] = acc[yy][0][ch][r] + bia0[r];
                    v1[r] = acc[yy][1][ch][r] + bia1[r];
                }
                if (g < 2) {
                    #pragma unroll
                    for (int r = 0; r < 4; ++r)
                        out[(long long)(3 + 4 * g + r) * HW + pg] = v0[r];
                }
                float s[4];
                int kbase;
                if (g < 2) {
                    kbase = 8 + 4 * g;
                    #pragma unroll
                    for (int r = 0; r < 4; ++r) s[r] = v1[r] * 0.2f;
                } else {
                    kbase = 4 * (g - 2);
                    #pragma unroll
                    for (int r = 0; r < 4; ++r) s[r] = v0[r] * 0.2f;
                }
                float m = fmaxf(fmaxf(s[0], s[1]), fmaxf(s[2], s[3]));
                m = fmaxf(m, __shfl_xor(m, 16));
                m = fmaxf(m, __shfl_xor(m, 32));
                float e[4], loc = 0.f;
                #pragma unroll
                for (int r = 0; r < 4; ++r) { e[r] = __expf(s[r] - m); loc += e[r]; }
                loc += __shfl_xor(loc, 16);
                loc += __shfl_xor(loc, 32);
                float inv = 1.f / loc;
                long long pl = (long long)(gy - row0) * IMG + col;
                u16x4 pk;
                #pragma unroll
                for (int r = 0; r < 4; ++r) pk[r] = f2bf(e[r] * inv);
                *(u16x4*)&wsoft[pl * 16 + kbase] = pk;
            }
        }
    }
}

// ---------------- filter v3: bf16 channel-last wsoft, 4 px/thread ----------
__global__ __launch_bounds__(256) void apply_filter(
    const float* __restrict__ x, const float* __restrict__ dwk,
    const u16* __restrict__ wsoft, float* __restrict__ out,
    long long wss, int row0, int nrows)
{
    constexpr int PAD = 4, TSF = 40;             // 32+8
    __shared__ float ctile[3][TSF * TSF];        // 19.2 KB

    const int tid = threadIdx.x;
    const int tx = tid & 7, ty = tid >> 3;
    const int bx = blockIdx.x * 32;
    const int gy0 = row0 + blockIdx.y * 32;
    x     += (long long)blockIdx.z * 20 * HW;
    out   += (long long)blockIdx.z * 11 * HW;
    wsoft += (long long)blockIdx.z * wss;

    for (int c = 0; c < 3; ++c)
        for (int idx = tid; idx < TSF * TSF; idx += 256) {
            int ly = idx / TSF, lx = idx - ly * TSF;
            int gy = gy0 + ly - PAD, gx = bx + lx - PAD;
            float v = 0.f;
            if (gy >= 0 && gy < IMG && gx >= 0 && gx < IMG)
                v = x[(long long)c * HW + (long long)gy * IMG + gx];
            ctile[c][idx] = v;
        }
    __syncthreads();

    const int gy = gy0 + ty;
    const int xq = bx + tx * 4;

    float wreg[16][4];
    #pragma unroll
    for (int p = 0; p < 4; ++p) {
        long long pb = ((long long)(gy - row0) * IMG + xq + p) * 16;
        u16x8 lo = *(const u16x8*)&wsoft[pb];
        u16x8 hi = *(const u16x8*)&wsoft[pb + 8];
        #pragma unroll
        for (int k = 0; k < 8; ++k) {
            wreg[k][p]     = bf2f(lo[k]);
            wreg[8 + k][p] = bf2f(hi[k]);
        }
    }

    float f[3][4];
    #pragma unroll
    for (int c = 0; c < 3; ++c)
        #pragma unroll
        for (int p = 0; p < 4; ++p) f[c][p] = 0.f;

    for (int dy = 0; dy < 9; ++dy) {
        float c9[9][4];
        #pragma unroll
        for (int dxx = 0; dxx < 9; ++dxx)
            #pragma unroll
            for (int p = 0; p < 4; ++p) c9[dxx][p] = 0.f;
        #pragma unroll
        for (int k = 0; k < 16; ++k) {
            #pragma unroll
            for (int dxx = 0; dxx < 9; ++dxx) {
                float s = dwk[k * 81 + dy * 9 + dxx];   // wave-uniform -> s_load
                #pragma unroll
                for (int p = 0; p < 4; ++p) c9[dxx][p] += s * wreg[k][p];
            }
        }
        #pragma unroll
        for (int c = 0; c < 3; ++c) {
            const float* crow = &ctile[c][(ty + dy) * TSF + tx * 4];
            f32x4 q0 = *(const f32x4*)crow;
            f32x4 q1 = *(const f32x4*)(crow + 4);
            f32x4 q2 = *(const f32x4*)(crow + 8);
            float win[12];
            #pragma unroll
            for (int j = 0; j < 4; ++j) { win[j] = q0[j]; win[4 + j] = q1[j]; win[8 + j] = q2[j]; }
            #pragma unroll
            for (int dxx = 0; dxx < 9; ++dxx)
                #pragma unroll
                for (int p = 0; p < 4; ++p)
                    f[c][p] += c9[dxx][p] * win[dxx + p];
        }
    }

    #pragma unroll
    for (int c = 0; c < 3; ++c) {
        f32x4 o = { f[c][0], f[c][1], f[c][2], f[c][3] };
        *(f32x4*)&out[(long long)c * HW + (long long)gy * IMG + xq] = o;
    }
}

static inline int hmax(int a, int b) { return a > b ? a : b; }
static inline int hmin(int a, int b) { return a < b ? a : b; }

extern "C" void kernel_launch(void* const* d_in, const int* in_sizes, int n_in,
                              void* d_out, int out_size, void* d_ws, size_t ws_size,
                              hipStream_t stream) {
    const float* x   = (const float*)d_in[0];
    const float* w1  = (const float*)d_in[1];
    const float* b1  = (const float*)d_in[2];
    const float* w2  = (const float*)d_in[3];
    const float* b2  = (const float*)d_in[4];
    const float* w3  = (const float*)d_in[5];
    const float* b3  = (const float*)d_in[6];
    const float* w4  = (const float*)d_in[7];
    const float* b4  = (const float*)d_in[8];
    const float* dwk = (const float*)d_in[9];
    float* out = (float*)d_out;

    // Both batches resident: footprint is 2x per-batch buffers + weights.
    // R must be a multiple of 64 for the 4-tile pipelined conv3/conv4.
    int R = 64;
    const int cand[5] = {1024, 512, 256, 128, 64};
    for (int i = 0; i < 5; ++i) {
        long long r = cand[i];
        size_t per_batch = 32768ULL * (r + 12) + 65536ULL * (r + 8)
                         + 131072ULL * (r + 4) + 32768ULL * r;
        size_t need = 2 * per_batch + 400000ULL;
        if (need <= ws_size) { R = cand[i]; break; }
    }

    const long long h1s = (long long)(R + 12) * IMG * 16;
    const long long h2s = (long long)(R + 8) * IMG * 32;
    const long long h3s = (long long)(R + 4) * IMG * 64;
    const long long wss = (long long)R * IMG * 16;

    u16* h1    = (u16*)d_ws;                      // 2 x h1s
    u16* h2    = h1 + 2 * h1s;                    // 2 x h2s
    u16* h3    = h2 + 2 * h2s;                    // 2 x h3s
    u16* wsoft = h3 + 2 * h3s;                    // 2 x wss (bf16 CL [px][16])
    u16* w1p   = wsoft + 2 * wss;
    u16* w2p   = w1p + 49 * 16 * 32;
    u16* w3p   = w2p + 13 * 32 * 32;
    u16* w4p   = w3p + 25 * 64 * 32;

    dim3 blk(256);
    prep_all<<<dim3(550), blk, 0, stream>>>(w1, w2, w3, w4, w1p, w2p, w3p, w4p);

    const int nstripes = IMG / R;
    for (int s = 0; s < nstripes; ++s) {
        const int r0 = s * R;
        const int h1_lo = hmax(0, r0 - 6), h1_hi = hmin(IMG, r0 + R + 6), h1_r = h1_hi - h1_lo;
        const int h2_lo = hmax(0, r0 - 4), h2_hi = hmin(IMG, r0 + R + 4), h2_r = h2_hi - h2_lo;
        const int h3_lo = hmax(0, r0 - 2), h3_hi = hmin(IMG, r0 + R + 2), h3_r = h3_hi - h3_lo;

        conv1_mfma<<<dim3(64, (h1_r + 15) / 16, 2), blk, 0, stream>>>(
            x, w1p, b1, h1, h1s, h1_lo, h1_r);
        conv2_mfma<<<dim3(64, (h2_r + 15) / 16, 2), blk, 0, stream>>>(
            h1, w2p, b2, h2, h1s, h2s, h1_lo, h1_r, h2_lo, h2_r);
        conv3_mfma<<<dim3(64, (h3_r + 63) / 64, 2), blk, 0, stream>>>(
            h2, w3p, b3, h3, h2s, h3s, h2_lo, h2_r, h3_lo, h3_r);
        conv4_mfma<<<dim3(32, R / 64, 2), blk, 0, stream>>>(
            h3, w4p, b4, out, wsoft, h3s, wss, h3_lo, h3_r, r0, R);
        apply_filter<<<dim3(32, R / 32, 2), blk, 0, stream>>>(
            x, dwk, wsoft, out, wss, r0, R);
    }
}

// Round 24
// 1014.693 us; speedup vs baseline: 1.0473x; 1.0090x over previous
//
#include <hip/hip_runtime.h>

constexpr int IMG = 1024;
constexpr long long HW = (long long)IMG * IMG;

typedef unsigned short u16;
typedef __attribute__((ext_vector_type(8))) short bf16x8;
typedef __attribute__((ext_vector_type(4))) float f32x4;
typedef __attribute__((ext_vector_type(4))) u16 u16x4;
typedef __attribute__((ext_vector_type(8))) u16 u16x8;

__device__ __forceinline__ int reflect_idx(int i, int n) {
    if (i < 0) i = -i;
    if (i >= n) i = 2 * n - 2 - i;
    return i;
}
__device__ __forceinline__ int iclamp(int v, int lo, int hi) {
    return v < lo ? lo : (v > hi ? hi : v);
}
__device__ __forceinline__ u16 f2bf(float f) {
    unsigned u = __builtin_bit_cast(unsigned, f);
    u += 0x7FFF + ((u >> 16) & 1);
    return (u16)(u >> 16);
}
__device__ __forceinline__ float bf2f(u16 v) {
    unsigned u = ((unsigned)v) << 16;
    return __builtin_bit_cast(float, u);
}

// ---------------- merged weight prepack (one launch) ----------------
__global__ void prep_all(
    const float* __restrict__ w1, const float* __restrict__ w2,
    const float* __restrict__ w3, const float* __restrict__ w4,
    u16* __restrict__ w1p, u16* __restrict__ w2p,
    u16* __restrict__ w3p, u16* __restrict__ w4p)
{
    int i = blockIdx.x * 256 + threadIdx.x;
    if (i < 25088) {                               // w1p [tap49][co16][ci32]
        int tap = i / (16 * 32), rem = i % (16 * 32), co = rem / 32, ci = rem % 32;
        w1p[i] = (ci < 20) ? f2bf(w1[(co * 20 + ci) * 49 + tap]) : (u16)0;
        return;
    }
    i -= 25088;
    if (i < 13312) {                               // w2p [pair13][co32][k32]
        int p = i / (32 * 32), rem = i % (32 * 32), co = rem / 32, k = rem % 32;
        int tap = 2 * p + (k >> 4), ci = k & 15;
        w2p[i] = (tap < 25) ? f2bf(w2[(co * 16 + ci) * 25 + tap]) : (u16)0;
        return;
    }
    i -= 13312;
    if (i < 51200) {                               // w3p [tap25][co64][ci32]
        int tap = i / (64 * 32), rem = i % (64 * 32), co = rem / 32, ci = rem % 32;
        w3p[i] = f2bf(w3[(co * 32 + ci) * 25 + tap]);
        return;
    }
    i -= 51200;
    if (i < 51200) {                               // w4p [tap25][co32pad][ci64]
        int tap = i / (32 * 64), rem = i % (32 * 64), co = rem / 64, ci = rem % 64;
        w4p[i] = (co < 24) ? f2bf(w4[(co * 64 + ci) * 25 + tap]) : (u16)0;
    }
}

// ---------------- conv1 MFMA: 20(pad32)->16, 7x7, planar fp32 in, CL bf16 out
__global__ __launch_bounds__(256) void conv1_mfma(
    const float* __restrict__ x, const u16* __restrict__ w1p,
    const float* __restrict__ b1, u16* __restrict__ h1, long long h1s,
    int out_base, int out_rows)
{
    constexpr int TS = 22, PAD = 3, UNITS = 4;
    __shared__ u16 tile[TS * TS * 32];           // 31 KB

    const int tid = threadIdx.x;
    const int gx0 = blockIdx.x * 16;
    const int gy0 = out_base + blockIdx.y * 16;
    x  += (long long)blockIdx.z * 20 * HW;
    h1 += (long long)blockIdx.z * h1s;

    for (int u = tid; u < TS * TS * UNITS; u += 256) {
        int pu = u >> 2, q = u & 3;
        int ty = pu / TS, tx = pu - ty * TS;
        int gy = reflect_idx(gy0 + ty - PAD, IMG);
        int gx = reflect_idx(gx0 + tx - PAD, IMG);
        long long off = (long long)gy * IMG + gx;
        bf16x8 v;
        #pragma unroll
        for (int j = 0; j < 8; ++j) {
            int cc = q * 8 + j;
            float f = (cc < 20) ? x[(long long)cc * HW + off] : 0.f;
            v[j] = (short)f2bf(f);
        }
        *(bf16x8*)&tile[(pu * UNITS + (q ^ (tx & 3))) * 8] = v;
    }
    __syncthreads();

    const int lane = tid & 63, wv = tid >> 6;
    const int l15 = lane & 15, g = lane >> 4;

    f32x4 acc[4];
    #pragma unroll
    for (int y = 0; y < 4; ++y) acc[y] = (f32x4){0.f, 0.f, 0.f, 0.f};

    const u16* wp = w1p;
    for (int dx = 0; dx < 7; ++dx) {
        asm volatile("" : "+s"(wp));             // re-opaque per dx: no cross-dx hoist
        bf16x8 af[7];
        #pragma unroll
        for (int dy = 0; dy < 7; ++dy)
            af[dy] = *(const bf16x8*)&wp[((dy * 7 + dx) * 16 + l15) * 32 + g * 8];
        bf16x8 bfr[10];
        const int tx = l15 + dx;
        #pragma unroll
        for (int r = 0; r < 10; ++r)
            bfr[r] = *(const bf16x8*)&tile[(((wv * 4 + r) * TS + tx) * UNITS + (g ^ (tx & 3))) * 8];
        #pragma unroll
        for (int yy = 0; yy < 4; ++yy)
            #pragma unroll
            for (int dy = 0; dy < 7; ++dy)
                acc[yy] = __builtin_amdgcn_mfma_f32_16x16x32_bf16(af[dy], bfr[yy + dy], acc[yy], 0, 0, 0);
    }

    const int out_hi = out_base + out_rows;
    float bia[4];
    #pragma unroll
    for (int r = 0; r < 4; ++r) bia[r] = b1[4 * g + r];
    #pragma unroll
    for (int yy = 0; yy < 4; ++yy) {
        int gy = gy0 + wv * 4 + yy;
        if (gy >= out_hi) continue;
        u16x4 pk;
        #pragma unroll
        for (int r = 0; r < 4; ++r)
            pk[r] = f2bf(fmaxf(acc[yy][r] + bia[r], 0.f));
        *(u16x4*)&h1[((long long)(gy - out_base) * IMG + gx0 + l15) * 16 + 4 * g] = pk;
    }
}

// ---------------- conv2 MFMA: 16->32, 5x5, pipelined 4-tile + DMA staging ---
// DMA staging (swizzle folded into source; LDS padded 800->832 units so all
// 13 wave-groups are full-wave, padded lanes read clamped valid addresses
// into never-read padding). 4-tile double buffer + per-p opaque wp.
__global__ __launch_bounds__(256) void conv2_mfma(
    const u16* __restrict__ h1, const u16* __restrict__ w2p,
    const float* __restrict__ b2, u16* __restrict__ h2,
    long long h1s, long long h2s,
    int in_base, int in_rows, int out_base, int out_rows)
{
    constexpr int TS = 20, PAD = 2, UNITS = 2;
    __shared__ u16 tileA[832 * 8];               // 13 KB (800 real + 32 pad units)
    __shared__ u16 tileB[832 * 8];

    const int tid = threadIdx.x;
    const int gx0 = blockIdx.x * 16;
    const int gy0_0 = out_base + blockIdx.y * 64;
    const int lane = tid & 63, wv = tid >> 6;
    const int l15 = lane & 15, g = lane >> 4;
    const int out_hi = out_base + out_rows;
    h1 += (long long)blockIdx.z * h1s;
    h2 += (long long)blockIdx.z * h2s;

    auto STAGE = [&](u16* tl, int gy0) {
        for (int gidx = wv; gidx < 13; gidx += 4) {
            int j = (gidx << 6) + lane;          // unit 0..831
            int jc = j < 800 ? j : 799;          // clamp padding lanes to a valid src
            int pu = jc >> 1, qq = jc & 1;
            int ty = pu / TS, tx = pu - ty * TS;
            int gy = iclamp(reflect_idx(gy0 + ty - PAD, IMG) - in_base, 0, in_rows - 1);
            int gx = reflect_idx(gx0 + tx - PAD, IMG);
            const u16* src = &h1[((long long)gy * IMG + gx) * 16 + ((qq ^ (tx & 1)) << 3)];
            __builtin_amdgcn_global_load_lds(
                (const __attribute__((address_space(1))) void*)src,
                (__attribute__((address_space(3))) void*)&tl[(long long)gidx << 9],
                16, 0, 0);
        }
    };

    auto COMPUTE_EPI = [&](const u16* tl, int gy0) {
        f32x4 acc[4][2];
        #pragma unroll
        for (int y = 0; y < 4; ++y) {
            acc[y][0] = (f32x4){0.f, 0.f, 0.f, 0.f};
            acc[y][1] = (f32x4){0.f, 0.f, 0.f, 0.f};
        }

        const u16* wp = w2p;
        for (int p = 0; p < 13; ++p) {
            asm volatile("" : "+s"(wp));         // re-opaque per p: no hoist
            int tap = 2 * p + (g >> 1);
            int tb = tap > 24 ? 24 : tap;        // pad tap: A is zero, B content irrelevant
            int dy = tb / 5, dx = tb - dy * 5;
            bf16x8 af0 = *(const bf16x8*)&wp[(p * 32 + l15) * 32 + g * 8];
            bf16x8 af1 = *(const bf16x8*)&wp[(p * 32 + 16 + l15) * 32 + g * 8];
            const int tx = l15 + dx;
            #pragma unroll
            for (int yy = 0; yy < 4; ++yy) {
                int ty = wv * 4 + yy + dy;
                bf16x8 bf = *(const bf16x8*)&tl[((ty * TS + tx) * UNITS + ((g & 1) ^ (tx & 1))) * 8];
                acc[yy][0] = __builtin_amdgcn_mfma_f32_16x16x32_bf16(af0, bf, acc[yy][0], 0, 0, 0);
                acc[yy][1] = __builtin_amdgcn_mfma_f32_16x16x32_bf16(af1, bf, acc[yy][1], 0, 0, 0);
            }
        }

        #pragma unroll
        for (int yy = 0; yy < 4; ++yy) {
            int gy = gy0 + wv * 4 + yy;
            if (gy >= out_hi) continue;
            long long pb = ((long long)(gy - out_base) * IMG + gx0 + l15) * 32;
            #pragma unroll
            for (int cb = 0; cb < 2; ++cb) {
                int co = cb * 16 + 4 * g;
                u16x4 pk;
                #pragma unroll
                for (int r = 0; r < 4; ++r)
                    pk[r] = f2bf(fmaxf(acc[yy][cb][r] + b2[co + r], 0.f));
                *(u16x4*)&h2[pb + co] = pk;
            }
        }
    };

    STAGE(tileA, gy0_0);
    for (int t = 0; t < 4; ++t) {
        const int gy0 = gy0_0 + t * 16;
        if (gy0 >= out_hi) break;                 // block-uniform: safe with barriers
        const u16* cur  = (t & 1) ? tileB : tileA;
        u16*       next = (t & 1) ? tileA : tileB;
        __syncthreads();                          // drain cur's stage; next's readers done
        if (t < 3) STAGE(next, gy0 + 16);
        COMPUTE_EPI(cur, gy0);
    }
}

// ---------------- conv3 MFMA: 32->64, 5x5, pipelined 4-tile + opaque wp -----
// 16-wide tiles (R21 optimum; 32-wide regressed: acc 128 + bf 64 blows the
// register slack). Double-buffered DMA pipeline, per-dy opaque weight ptr.
__global__ __launch_bounds__(256) void conv3_mfma(
    const u16* __restrict__ h2, const u16* __restrict__ w3p,
    const float* __restrict__ b3, u16* __restrict__ h3,
    long long h2s, long long h3s,
    int in_base, int in_rows, int out_base, int out_rows)
{
    constexpr int CI = 32, TS = 20, PAD = 2, UNITS = 4;
    __shared__ u16 tileA[TS * TS * CI];          // 25.6 KB (even tiles)
    __shared__ u16 tileB[TS * TS * CI];          // 25.6 KB (odd tiles)

    const int tid = threadIdx.x;
    const int gx0 = blockIdx.x * 16;
    const int gy0_0 = out_base + blockIdx.y * 64;
    const int lane = tid & 63, wv = tid >> 6;
    const int l15 = lane & 15, g = lane >> 4;
    const int out_hi = out_base + out_rows;
    h2 += (long long)blockIdx.z * h2s;
    h3 += (long long)blockIdx.z * h3s;

    auto STAGE = [&](u16* tl, int gy0) {
        for (int gidx = wv; gidx < 25; gidx += 4) {
            int j = (gidx << 6) + lane;
            int pu = j >> 2, qq = j & 3;
            int ty = pu / TS, tx = pu - ty * TS;
            int gy = iclamp(reflect_idx(gy0 + ty - PAD, IMG) - in_base, 0, in_rows - 1);
            int gx = reflect_idx(gx0 + tx - PAD, IMG);
            const u16* src = &h2[((long long)gy * IMG + gx) * CI + ((qq ^ (tx & 3)) << 3)];
            __builtin_amdgcn_global_load_lds(
                (const __attribute__((address_space(1))) void*)src,
                (__attribute__((address_space(3))) void*)&tl[(long long)gidx << 9],
                16, 0, 0);
        }
    };

    auto COMPUTE_EPI = [&](const u16* tl, int gy0) {
        f32x4 acc[4][4];
        #pragma unroll
        for (int y = 0; y < 4; ++y)
            #pragma unroll
            for (int cb = 0; cb < 4; ++cb) acc[y][cb] = (f32x4){0.f, 0.f, 0.f, 0.f};

        const u16* wp = w3p;
        for (int dx = 0; dx < 5; ++dx) {
            const int tx = l15 + dx;
            const int uu = g ^ (tx & 3);
            bf16x8 bfr[8];
            #pragma unroll
            for (int s = 0; s < 8; ++s)
                bfr[s] = *(const bf16x8*)&tl[(((wv * 4 + s) * TS + tx) * UNITS + uu) * 8];
            #pragma unroll
            for (int dy = 0; dy < 5; ++dy) {
                asm volatile("" : "+s"(wp));     // re-opaque per dy: no hoist
                const int tap = dy * 5 + dx;
                bf16x8 af[4];
                #pragma unroll
                for (int cb = 0; cb < 4; ++cb)
                    af[cb] = *(const bf16x8*)&wp[(tap * 64 + cb * 16 + l15) * 32 + g * 8];
                #pragma unroll
                for (int yy = 0; yy < 4; ++yy)
                    #pragma unroll
                    for (int cb = 0; cb < 4; ++cb)
                        acc[yy][cb] = __builtin_amdgcn_mfma_f32_16x16x32_bf16(af[cb], bfr[yy + dy], acc[yy][cb], 0, 0, 0);
            }
        }

        #pragma unroll
        for (int yy = 0; yy < 4; ++yy) {
            int gy = gy0 + wv * 4 + yy;
            if (gy >= out_hi) continue;
            long long pb = ((long long)(gy - out_base) * IMG + gx0 + l15) * 64;
            #pragma unroll
            for (int cb = 0; cb < 4; ++cb) {
                int co = cb * 16 + 4 * g;
                u16x4 pk;
                #pragma unroll
                for (int r = 0; r < 4; ++r)
                    pk[r] = f2bf(fmaxf(acc[yy][cb][r] + b3[co + r], 0.f));
                *(u16x4*)&h3[pb + co] = pk;
            }
        }
    };

    STAGE(tileA, gy0_0);
    for (int t = 0; t < 4; ++t) {
        const int gy0 = gy0_0 + t * 16;
        if (gy0 >= out_hi) break;                 // block-uniform: safe with barriers
        const u16* cur  = (t & 1) ? tileB : tileA;
        u16*       next = (t & 1) ? tileA : tileB;
        __syncthreads();                          // drain cur's stage; next's readers done
        if (t < 3) STAGE(next, gy0 + 16);
        COMPUTE_EPI(cur, gy0);
    }
}

// ---------------- conv4 MFMA: 64->24(+8 pad), 5x5 + softmax, 32-wide tiles --
__global__ __launch_bounds__(256) void conv4_mfma(
    const u16* __restrict__ h3, const u16* __restrict__ w4p,
    const float* __restrict__ b4, float* __restrict__ out,
    u16* __restrict__ wsoft, long long h3s, long long wss,
    int in_base, int in_rows, int row0, int nrows)
{
    constexpr int CI = 64, TSY = 20, TSX = 36, PAD = 2, UNITS = 4;
    __shared__ u16 tileA[TSY * TSX * 32];        // 45 KB (even steps)
    __shared__ u16 tileB[TSY * TSX * 32];        // 45 KB (odd steps)

    const int tid = threadIdx.x;
    const int gx0 = blockIdx.x * 32;
    const int gy0_0 = row0 + blockIdx.y * 64;
    const int lane = tid & 63, wv = tid >> 6;
    const int l15 = lane & 15, g = lane >> 4;
    h3    += (long long)blockIdx.z * h3s;
    out   += (long long)blockIdx.z * 11 * HW;
    wsoft += (long long)blockIdx.z * wss;

    auto STAGE = [&](u16* tl, int gy0, int half) {
        for (int gidx = wv; gidx < 45; gidx += 4) {   // 45 groups x 64 units = 20*36*4
            int j = (gidx << 6) + lane;
            int pu = j >> 2, qq = j & 3;
            int ty = pu / TSX, tx = pu - ty * TSX;
            int gy = iclamp(reflect_idx(gy0 + ty - PAD, IMG) - in_base, 0, in_rows - 1);
            int gx = reflect_idx(gx0 + tx - PAD, IMG);
            const u16* src = &h3[((long long)gy * IMG + gx) * CI + half * 32 + ((qq ^ (tx & 3)) << 3)];
            __builtin_amdgcn_global_load_lds(
                (const __attribute__((address_space(1))) void*)src,
                (__attribute__((address_space(3))) void*)&tl[(long long)gidx << 9],
                16, 0, 0);
        }
    };

    auto COMPUTE = [&](const u16* tl, int half, f32x4 (&acc)[4][2][2]) {
        for (int dx = 0; dx < 5; ++dx) {
            const int txL = l15 + dx;             // left col-half
            const int txR = txL + 16;             // right col-half ((txR&3)==(txL&3))
            const int uu = g ^ (txL & 3);
            bf16x8 bfL[8], bfR[8];
            #pragma unroll
            for (int s = 0; s < 8; ++s) {
                bfL[s] = *(const bf16x8*)&tl[(((wv * 4 + s) * TSX + txL) * UNITS + uu) * 8];
                bfR[s] = *(const bf16x8*)&tl[(((wv * 4 + s) * TSX + txR) * UNITS + uu) * 8];
            }
            #pragma unroll
            for (int dy = 0; dy < 5; ++dy) {
                const int tap = dy * 5 + dx;
                bf16x8 af0 = *(const bf16x8*)&w4p[(tap * 32 + l15) * 64 + half * 32 + g * 8];
                bf16x8 af1 = *(const bf16x8*)&w4p[(tap * 32 + 16 + l15) * 64 + half * 32 + g * 8];
                #pragma unroll
                for (int yy = 0; yy < 4; ++yy) {
                    acc[yy][0][0] = __builtin_amdgcn_mfma_f32_16x16x32_bf16(af0, bfL[yy + dy], acc[yy][0][0], 0, 0, 0);
                    acc[yy][1][0] = __builtin_amdgcn_mfma_f32_16x16x32_bf16(af1, bfL[yy + dy], acc[yy][1][0], 0, 0, 0);
                    acc[yy][0][1] = __builtin_amdgcn_mfma_f32_16x16x32_bf16(af0, bfR[yy + dy], acc[yy][0][1], 0, 0, 0);
                    acc[yy][1][1] = __builtin_amdgcn_mfma_f32_16x16x32_bf16(af1, bfR[yy + dy], acc[yy][1][1], 0, 0, 0);
                }
            }
        }
    };

    float bia0[4], bia1[4];
    #pragma unroll
    for (int r = 0; r < 4; ++r) {
        bia0[r] = b4[4 * g + r];
        int c1 = 16 + 4 * g + r;
        bia1[r] = (c1 < 24) ? b4[c1] : 0.f;
    }

    STAGE(tileA, gy0_0, 0);
    for (int t = 0; t < 4; ++t) {
        const int gy0 = gy0_0 + t * 16;
        f32x4 acc[4][2][2];                       // [row][co_blk][col_half]
        #pragma unroll
        for (int y = 0; y < 4; ++y)
            #pragma unroll
            for (int cb = 0; cb < 2; ++cb) {
                acc[y][cb][0] = (f32x4){0.f, 0.f, 0.f, 0.f};
                acc[y][cb][1] = (f32x4){0.f, 0.f, 0.f, 0.f};
            }

        __syncthreads();                          // drain A(half0); B readers done
        STAGE(tileB, gy0, 1);
        COMPUTE(tileA, 0, acc);
        __syncthreads();                          // drain B(half1); A readers done
        if (t < 3) STAGE(tileA, gy0 + 16, 0);
        COMPUTE(tileB, 1, acc);

        // epilogue per column-half: bias + hidden + softmax + bf16 wsoft store
        #pragma unroll
        for (int ch = 0; ch < 2; ++ch) {
            const int col = gx0 + ch * 16 + l15;
            #pragma unroll
            for (int yy = 0; yy < 4; ++yy) {
                int gy = gy0 + wv * 4 + yy;
                long long pg = (long long)gy * IMG + col;
                float v0[4], v1[4];
                #pragma unroll
                for (int r = 0; r < 4; ++r) {
                    v0[r] = acc[yy][0][ch][r] + bia0[r];
                    v1[r] = acc[yy][1][ch][r] + bia1[r];
                }
                if (g < 2) {
                    #pragma unroll
                    for (int r = 0; r < 4; ++r)
                        out[(long long)(3 + 4 * g + r) * HW + pg] = v0[r];
                }
                float s[4];
                int kbase;
                if (g < 2) {
                    kbase = 8 + 4 * g;
                    #pragma unroll
                    for (int r = 0; r < 4; ++r) s[r] = v1[r] * 0.2f;
                } else {
                    kbase = 4 * (g - 2);
                    #pragma unroll
                    for (int r = 0; r < 4; ++r) s[r] = v0[r] * 0.2f;
                }
                float m = fmaxf(fmaxf(s[0], s[1]), fmaxf(s[2], s[3]));
                m = fmaxf(m, __shfl_xor(m, 16));
                m = fmaxf(m, __shfl_xor(m, 32));
                float e[4], loc = 0.f;
                #pragma unroll
                for (int r = 0; r < 4; ++r) { e[r] = __expf(s[r] - m); loc += e[r]; }
                loc += __shfl_xor(loc, 16);
                loc += __shfl_xor(loc, 32);
                float inv = 1.f / loc;
                long long pl = (long long)(gy - row0) * IMG + col;
                u16x4 pk;
                #pragma unroll
                for (int r = 0; r < 4; ++r) pk[r] = f2bf(e[r] * inv);
                *(u16x4*)&wsoft[pl * 16 + kbase] = pk;
            }
        }
    }
}

// ---------------- filter v3: bf16 channel-last wsoft, 4 px/thread ----------
__global__ __launch_bounds__(256) void apply_filter(
    const float* __restrict__ x, const float* __restrict__ dwk,
    const u16* __restrict__ wsoft, float* __restrict__ out,
    long long wss, int row0, int nrows)
{
    constexpr int PAD = 4, TSF = 40;             // 32+8
    __shared__ float ctile[3][TSF * TSF];        // 19.2 KB

    const int tid = threadIdx.x;
    const int tx = tid & 7, ty = tid >> 3;
    const int bx = blockIdx.x * 32;
    const int gy0 = row0 + blockIdx.y * 32;
    x     += (long long)blockIdx.z * 20 * HW;
    out   += (long long)blockIdx.z * 11 * HW;
    wsoft += (long long)blockIdx.z * wss;

    for (int c = 0; c < 3; ++c)
        for (int idx = tid; idx < TSF * TSF; idx += 256) {
            int ly = idx / TSF, lx = idx - ly * TSF;
            int gy = gy0 + ly - PAD, gx = bx + lx - PAD;
            float v = 0.f;
            if (gy >= 0 && gy < IMG && gx >= 0 && gx < IMG)
                v = x[(long long)c * HW + (long long)gy * IMG + gx];
            ctile[c][idx] = v;
        }
    __syncthreads();

    const int gy = gy0 + ty;
    const int xq = bx + tx * 4;

    float wreg[16][4];
    #pragma unroll
    for (int p = 0; p < 4; ++p) {
        long long pb = ((long long)(gy - row0) * IMG + xq + p) * 16;
        u16x8 lo = *(const u16x8*)&wsoft[pb];
        u16x8 hi = *(const u16x8*)&wsoft[pb + 8];
        #pragma unroll
        for (int k = 0; k < 8; ++k) {
            wreg[k][p]     = bf2f(lo[k]);
            wreg[8 + k][p] = bf2f(hi[k]);
        }
    }

    float f[3][4];
    #pragma unroll
    for (int c = 0; c < 3; ++c)
        #pragma unroll
        for (int p = 0; p < 4; ++p) f[c][p] = 0.f;

    for (int dy = 0; dy < 9; ++dy) {
        float c9[9][4];
        #pragma unroll
        for (int dxx = 0; dxx < 9; ++dxx)
            #pragma unroll
            for (int p = 0; p < 4; ++p) c9[dxx][p] = 0.f;
        #pragma unroll
        for (int k = 0; k < 16; ++k) {
            #pragma unroll
            for (int dxx = 0; dxx < 9; ++dxx) {
                float s = dwk[k * 81 + dy * 9 + dxx];   // wave-uniform -> s_load
                #pragma unroll
                for (int p = 0; p < 4; ++p) c9[dxx][p] += s * wreg[k][p];
            }
        }
        #pragma unroll
        for (int c = 0; c < 3; ++c) {
            const float* crow = &ctile[c][(ty + dy) * TSF + tx * 4];
            f32x4 q0 = *(const f32x4*)crow;
            f32x4 q1 = *(const f32x4*)(crow + 4);
            f32x4 q2 = *(const f32x4*)(crow + 8);
            float win[12];
            #pragma unroll
            for (int j = 0; j < 4; ++j) { win[j] = q0[j]; win[4 + j] = q1[j]; win[8 + j] = q2[j]; }
            #pragma unroll
            for (int dxx = 0; dxx < 9; ++dxx)
                #pragma unroll
                for (int p = 0; p < 4; ++p)
                    f[c][p] += c9[dxx][p] * win[dxx + p];
        }
    }

    #pragma unroll
    for (int c = 0; c < 3; ++c) {
        f32x4 o = { f[c][0], f[c][1], f[c][2], f[c][3] };
        *(f32x4*)&out[(long long)c * HW + (long long)gy * IMG + xq] = o;
    }
}

static inline int hmax(int a, int b) { return a > b ? a : b; }
static inline int hmin(int a, int b) { return a < b ? a : b; }

extern "C" void kernel_launch(void* const* d_in, const int* in_sizes, int n_in,
                              void* d_out, int out_size, void* d_ws, size_t ws_size,
                              hipStream_t stream) {
    const float* x   = (const float*)d_in[0];
    const float* w1  = (const float*)d_in[1];
    const float* b1  = (const float*)d_in[2];
    const float* w2  = (const float*)d_in[3];
    const float* b2  = (const float*)d_in[4];
    const float* w3  = (const float*)d_in[5];
    const float* b3  = (const float*)d_in[6];
    const float* w4  = (const float*)d_in[7];
    const float* b4  = (const float*)d_in[8];
    const float* dwk = (const float*)d_in[9];
    float* out = (float*)d_out;

    // Both batches resident: footprint is 2x per-batch buffers + weights.
    // R must be a multiple of 64 for the 4-tile pipelined conv2/conv3/conv4.
    int R = 64;
    const int cand[5] = {1024, 512, 256, 128, 64};
    for (int i = 0; i < 5; ++i) {
        long long r = cand[i];
        size_t per_batch = 32768ULL * (r + 12) + 65536ULL * (r + 8)
                         + 131072ULL * (r + 4) + 32768ULL * r;
        size_t need = 2 * per_batch + 400000ULL;
        if (need <= ws_size) { R = cand[i]; break; }
    }

    const long long h1s = (long long)(R + 12) * IMG * 16;
    const long long h2s = (long long)(R + 8) * IMG * 32;
    const long long h3s = (long long)(R + 4) * IMG * 64;
    const long long wss = (long long)R * IMG * 16;

    u16* h1    = (u16*)d_ws;                      // 2 x h1s
    u16* h2    = h1 + 2 * h1s;                    // 2 x h2s
    u16* h3    = h2 + 2 * h2s;                    // 2 x h3s
    u16* wsoft = h3 + 2 * h3s;                    // 2 x wss (bf16 CL [px][16])
    u16* w1p   = wsoft + 2 * wss;
    u16* w2p   = w1p + 49 * 16 * 32;
    u16* w3p   = w2p + 13 * 32 * 32;
    u16* w4p   = w3p + 25 * 64 * 32;

    dim3 blk(256);
    prep_all<<<dim3(550), blk, 0, stream>>>(w1, w2, w3, w4, w1p, w2p, w3p, w4p);

    const int nstripes = IMG / R;
    for (int s = 0; s < nstripes; ++s) {
        const int r0 = s * R;
        const int h1_lo = hmax(0, r0 - 6), h1_hi = hmin(IMG, r0 + R + 6), h1_r = h1_hi - h1_lo;
        const int h2_lo = hmax(0, r0 - 4), h2_hi = hmin(IMG, r0 + R + 4), h2_r = h2_hi - h2_lo;
        const int h3_lo = hmax(0, r0 - 2), h3_hi = hmin(IMG, r0 + R + 2), h3_r = h3_hi - h3_lo;

        conv1_mfma<<<dim3(64, (h1_r + 15) / 16, 2), blk, 0, stream>>>(
            x, w1p, b1, h1, h1s, h1_lo, h1_r);
        conv2_mfma<<<dim3(64, (h2_r + 63) / 64, 2), blk, 0, stream>>>(
            h1, w2p, b2, h2, h1s, h2s, h1_lo, h1_r, h2_lo, h2_r);
        conv3_mfma<<<dim3(64, (h3_r + 63) / 64, 2), blk, 0, stream>>>(
            h2, w3p, b3, h3, h2s, h3s, h2_lo, h2_r, h3_lo, h3_r);
        conv4_mfma<<<dim3(32, R / 64, 2), blk, 0, stream>>>(
            h3, w4p, b4, out, wsoft, h3s, wss, h3_lo, h3_r, r0, R);
        apply_filter<<<dim3(32, R / 32, 2), blk, 0, stream>>>(
            x, dwk, wsoft, out, wss, r0, R);
    }
}